// Round 15
// baseline (368.921 us; speedup 1.0000x reference)
//
#include <hip/hip_runtime.h>

#define N_PRE 1024
#define N_POST 2048
#define SEQ_LEN 4096

// Reference-verified numerics (R11 PASS): per C element two fp32 segment
// chains k in [0,512) and [512,1024), ascending, single accumulator each,
// combined rn(S1+S2). stim in {0,1} -> products exact -> FMA == mul+add.
// Scan: v = rn(rn(v*0.9f) + c), fire >= 1.0f, reset 0. DO NOT REORDER.
//
// Sparse (v6, PASS absmax 0.015625): skipping adds of exact +/-0.0 is
// BIT-IDENTICAL (acc starts +0.0; RN never yields -0.0 from a sum).
// Walk ascending per-t spike list: lo-chain k<512, hi-chain k>=512,
// write rn(lo+hi).
//
// v11/v12/v13 all 122-144us regardless of occupancy (77/44/51%) or batch
// width (8/16) or pipelining -> per-CU gather ceiling ~22 B/cyc/CU,
// consistent with L1 miss-queue limit (64 lines x 64B / 200cyc = 20).
// v14 EXPERIMENT: gather via global_load_lds DMA (no L1 allocation; tests
// whether DMA fills bypass the miss-queue path). List words staged to LDS
// once -> steady VMEM stream is pure DMAs -> counted vmcnt(8) ping-pong.
// Values and add order identical -> bit-exact.
#define KSPLIT 512

__device__ __forceinline__ float opaque(float x) {
  asm volatile("" : "+v"(x));
  return x;
}

__device__ __forceinline__ float load_dyn(const void* p, size_t idx, bool isbf) {
  if (isbf) {
    const unsigned short b = ((const unsigned short*)p)[idx];
    return __uint_as_float(((unsigned int)b) << 16);
  }
  return ((const float*)p)[idx];
}

// Input-dtype sniff (established: weights fp32, stim bf16; kept for safety).
__device__ __forceinline__ int sniff_flags(const void* W, const void* S, int tid,
                                           int* flags_sh) {
  if (tid < 64) {
    const unsigned short* uw = (const unsigned short*)W;
    const float f = fabsf(__uint_as_float(((unsigned int)uw[tid * 2]) << 16));
    const bool big = !(f < 64.f);
    const unsigned long long wb = __ballot(big);
    const unsigned short* us = (const unsigned short*)S;
    int hit = 0;
    for (int j = 0; j < 64; ++j) hit |= (us[tid * 128 + 2 * j] == 0x3F80u) ? 1 : 0;
    const unsigned long long sb = __ballot(hit != 0);
    if (tid == 0) *flags_sh = ((wb == 0ull) ? 1 : 0) | ((sb != 0ull) ? 2 : 0);
  }
  __syncthreads();
  return *flags_sh;
}

// ---------------- WT build: W[n][k] -> WT[k][n] (fp32), LDS transpose -------
__global__ __launch_bounds__(256) void snn_wt_build(const void* __restrict__ W,
                                                    const void* __restrict__ S,
                                                    float* __restrict__ WT) {
  __shared__ float tile[64][65];
  __shared__ int flags_sh;
  const int tid = threadIdx.x;
  const int fl = sniff_flags(W, S, tid, &flags_sh);
  const bool w_bf = (fl & 1) != 0;
  const int k0 = blockIdx.x * 64;
  const int nn0 = blockIdx.y * 64;
  {
    const int r = tid >> 2;
    const int cq = tid & 3;
    if (!w_bf) {
      const float* Wf = (const float*)W;
#pragma unroll
      for (int p = 0; p < 4; ++p) {
        const int c = cq * 16 + p * 4;
        const float4 va = *(const float4*)&Wf[(size_t)(nn0 + r) * N_PRE + k0 + c];
        tile[c + 0][r] = va.x; tile[c + 1][r] = va.y;
        tile[c + 2][r] = va.z; tile[c + 3][r] = va.w;
      }
    } else {
#pragma unroll
      for (int p = 0; p < 4; ++p)
#pragma unroll
        for (int j = 0; j < 4; ++j) {
          const int c = cq * 16 + p * 4 + j;
          tile[c][r] = load_dyn(W, (size_t)(nn0 + r) * N_PRE + k0 + c, true);
        }
    }
  }
  __syncthreads();
  {
    const int kr = tid >> 2;
    const int nq = tid & 3;
#pragma unroll
    for (int p = 0; p < 4; ++p) {
      const int c = nq * 16 + p * 4;
      float4 o;
      o.x = tile[kr][c + 0]; o.y = tile[kr][c + 1];
      o.z = tile[kr][c + 2]; o.w = tile[kr][c + 3];
      *(float4*)&WT[(size_t)(k0 + kr) * N_POST + nn0 + c] = o;
    }
  }
}

// ---------------- mask build: stim -> MT[t/8][k] bitmask bytes --------------
__global__ __launch_bounds__(64) void snn_mask_build(const void* __restrict__ W,
                                                     const void* __restrict__ S,
                                                     unsigned char* __restrict__ MT) {
  __shared__ int flags_sh;
  const int tid = threadIdx.x;
  const int fl = sniff_flags(W, S, tid, &flags_sh);
  const bool s_bf = (fl & 2) != 0;
  const int tb = blockIdx.x;  // t-byte index: t = tb*8 + bit
  unsigned wrd[4] = {0u, 0u, 0u, 0u};
#pragma unroll
  for (int kk = 0; kk < 16; ++kk) {
    const int k = tid * 16 + kk;
    unsigned byte = 0;
    if (s_bf) {
      const unsigned short* Sb = (const unsigned short*)S;
      const uint4 u = *(const uint4*)&Sb[(size_t)k * SEQ_LEN + tb * 8];
      byte |= (((u.x & 0x7FFFu) != 0u) ? 1u : 0u) << 0;
      byte |= (((u.x & 0x7FFF0000u) != 0u) ? 1u : 0u) << 1;
      byte |= (((u.y & 0x7FFFu) != 0u) ? 1u : 0u) << 2;
      byte |= (((u.y & 0x7FFF0000u) != 0u) ? 1u : 0u) << 3;
      byte |= (((u.z & 0x7FFFu) != 0u) ? 1u : 0u) << 4;
      byte |= (((u.z & 0x7FFF0000u) != 0u) ? 1u : 0u) << 5;
      byte |= (((u.w & 0x7FFFu) != 0u) ? 1u : 0u) << 6;
      byte |= (((u.w & 0x7FFF0000u) != 0u) ? 1u : 0u) << 7;
    } else {
      const float* Sf = (const float*)S;
      const size_t base = (size_t)k * SEQ_LEN + tb * 8;
      const float4 f0 = *(const float4*)&Sf[base];
      const float4 f1 = *(const float4*)&Sf[base + 4];
      byte |= ((f0.x != 0.0f) ? 1u : 0u) << 0;
      byte |= ((f0.y != 0.0f) ? 1u : 0u) << 1;
      byte |= ((f0.z != 0.0f) ? 1u : 0u) << 2;
      byte |= ((f0.w != 0.0f) ? 1u : 0u) << 3;
      byte |= ((f1.x != 0.0f) ? 1u : 0u) << 4;
      byte |= ((f1.y != 0.0f) ? 1u : 0u) << 5;
      byte |= ((f1.z != 0.0f) ? 1u : 0u) << 6;
      byte |= ((f1.w != 0.0f) ? 1u : 0u) << 7;
    }
    wrd[kk >> 2] |= byte << ((kk & 3) * 8);
  }
  *(uint4*)&MT[(size_t)tb * N_PRE + tid * 16] =
      make_uint4(wrd[0], wrd[1], wrd[2], wrd[3]);
}

// ---------------- list build: MT -> per-t ascending spike list --------------
__global__ __launch_bounds__(64) void snn_list_build(const unsigned char* __restrict__ MT,
                                                     unsigned short* __restrict__ lists,
                                                     int* __restrict__ lens) {
  const int t = blockIdx.x;
  const int l = threadIdx.x;
  const unsigned char* Mrow = MT + (size_t)(t >> 3) * N_PRE;
  const int bit = t & 7;
  unsigned short* Lp = lists + (size_t)t * N_PRE;
  int base = 0;
#pragma unroll
  for (int c = 0; c < 16; ++c) {
    const int k = c * 64 + l;
    const int b = (Mrow[k] >> bit) & 1;
    const unsigned long long m = __ballot(b != 0);
    const int pre = __popcll(m & ((1ull << l) - 1ull));
    if (b) Lp[base + pre] = (unsigned short)k;
    base += __popcll(m);
  }
  if (l == 0) lens[t] = base;
}

// ---------------- sparse GEMM: C[t][n] = sum over spiking k of WT[k][n] -----
// v14: gather via global_load_lds DMA. 64-thr blocks, slice = bid & 7 (XCD
// pinning, v11-verified). List words staged to LDS once -> steady VMEM
// stream = pure DMAs -> counted vmcnt(8) ping-pong (batch B's 8 DMAs in
// flight over batch A's ds_read+adds). Adds in ascending list order with
// lo/hi classification -> bit-identical to the [512|512] dense chains.
__global__ __launch_bounds__(64) void snn_gemm_sp(const float* __restrict__ WT,
                                                  const unsigned short* __restrict__ lists,
                                                  const int* __restrict__ lens,
                                                  float* __restrict__ C,
                                                  int t0, int ct) {
  __shared__ float rows[2][8][256];  // 16 KB DMA landing pads [buf][row][n]
  __shared__ uint4 lw[128];          // staged list words (<= N_PRE/8)
  const int slice = (int)blockIdx.x & 7;
  const int tl = (int)blockIdx.x >> 3;
  const int tg = t0 + tl;
  const int lane = (int)threadIdx.x;
  const int n = slice * 256 + lane * 4;
  const unsigned short* __restrict__ L16 = lists + (size_t)tg * N_PRE;
  const uint4* __restrict__ Lw = (const uint4*)L16;
  const int len = lens[tg];
  const int nb = len >> 3;  // full 8-entry batches

  float lo0 = 0.f, lo1 = 0.f, lo2 = 0.f, lo3 = 0.f;
  float hi0 = 0.f, hi1 = 0.f, hi2 = 0.f, hi3 = 0.f;
  int kA0, kA1, kA2, kA3, kA4, kA5, kA6, kA7;
  int kB0, kB1, kB2, kB3, kB4, kB5, kB6, kB7;

  // stage list words into LDS (single wave; drain before use)
  for (int w = lane; w < nb; w += 64) lw[w] = Lw[w];
  asm volatile("s_waitcnt vmcnt(0) lgkmcnt(0)" ::: "memory");
  __builtin_amdgcn_sched_barrier(0);

#define UNPACK_S(S, B)                                                   \
  {                                                                      \
    const uint4 u = lw[B];                                               \
    k##S##0 = u.x & 0xFFFF; k##S##1 = (int)(u.x >> 16);                  \
    k##S##2 = u.y & 0xFFFF; k##S##3 = (int)(u.y >> 16);                  \
    k##S##4 = u.z & 0xFFFF; k##S##5 = (int)(u.z >> 16);                  \
    k##S##6 = u.w & 0xFFFF; k##S##7 = (int)(u.w >> 16);                  \
  }
#define DMA_S(S, BUF)                                                                     \
  {                                                                                       \
    __builtin_amdgcn_global_load_lds(&WT[((size_t)k##S##0 << 11) + n], &rows[BUF][0][0],  \
                                     16, 0, 0);                                           \
    __builtin_amdgcn_global_load_lds(&WT[((size_t)k##S##1 << 11) + n], &rows[BUF][1][0],  \
                                     16, 0, 0);                                           \
    __builtin_amdgcn_global_load_lds(&WT[((size_t)k##S##2 << 11) + n], &rows[BUF][2][0],  \
                                     16, 0, 0);                                           \
    __builtin_amdgcn_global_load_lds(&WT[((size_t)k##S##3 << 11) + n], &rows[BUF][3][0],  \
                                     16, 0, 0);                                           \
    __builtin_amdgcn_global_load_lds(&WT[((size_t)k##S##4 << 11) + n], &rows[BUF][4][0],  \
                                     16, 0, 0);                                           \
    __builtin_amdgcn_global_load_lds(&WT[((size_t)k##S##5 << 11) + n], &rows[BUF][5][0],  \
                                     16, 0, 0);                                           \
    __builtin_amdgcn_global_load_lds(&WT[((size_t)k##S##6 << 11) + n], &rows[BUF][6][0],  \
                                     16, 0, 0);                                           \
    __builtin_amdgcn_global_load_lds(&WT[((size_t)k##S##7 << 11) + n], &rows[BUF][7][0],  \
                                     16, 0, 0);                                           \
  }
#define ACC_LO4(P)                                                       \
  { const float4 w_ = *(const float4*)(P);                               \
    lo0 += w_.x; lo1 += w_.y; lo2 += w_.z; lo3 += w_.w; }
#define ACC_HI4(P)                                                       \
  { const float4 w_ = *(const float4*)(P);                               \
    hi0 += w_.x; hi1 += w_.y; hi2 += w_.z; hi3 += w_.w; }
#define ACC_SEL4(K_, P)                                                  \
  { if ((K_) < KSPLIT) ACC_LO4(P) else ACC_HI4(P) }
#define CONSUME(S, BUF)                                                  \
  {                                                                      \
    const float* b_ = &rows[BUF][0][lane * 4];                           \
    if (k##S##7 < KSPLIT) {                                              \
      ACC_LO4(b_ + 0)    ACC_LO4(b_ + 256)  ACC_LO4(b_ + 512)            \
      ACC_LO4(b_ + 768)  ACC_LO4(b_ + 1024) ACC_LO4(b_ + 1280)           \
      ACC_LO4(b_ + 1536) ACC_LO4(b_ + 1792)                              \
    } else if (k##S##0 >= KSPLIT) {                                      \
      ACC_HI4(b_ + 0)    ACC_HI4(b_ + 256)  ACC_HI4(b_ + 512)            \
      ACC_HI4(b_ + 768)  ACC_HI4(b_ + 1024) ACC_HI4(b_ + 1280)           \
      ACC_HI4(b_ + 1536) ACC_HI4(b_ + 1792)                              \
    } else {                                                             \
      ACC_SEL4(k##S##0, b_ + 0)    ACC_SEL4(k##S##1, b_ + 256)           \
      ACC_SEL4(k##S##2, b_ + 512)  ACC_SEL4(k##S##3, b_ + 768)           \
      ACC_SEL4(k##S##4, b_ + 1024) ACC_SEL4(k##S##5, b_ + 1280)          \
      ACC_SEL4(k##S##6, b_ + 1536) ACC_SEL4(k##S##7, b_ + 1792)          \
    }                                                                    \
    asm volatile("s_waitcnt lgkmcnt(0)" ::: "memory");                   \
    __builtin_amdgcn_sched_barrier(0);                                   \
  }

  if (nb > 0) {
    UNPACK_S(A, 0)
    DMA_S(A, 0)
    int b = 0;
    for (; b + 2 <= nb; b += 2) {
      UNPACK_S(B, b + 1)
      DMA_S(B, 1)
      asm volatile("s_waitcnt vmcnt(8)" ::: "memory");  // A's 8 DMAs done
      __builtin_amdgcn_sched_barrier(0);
      CONSUME(A, 0)
      if (b + 2 < nb) {
        UNPACK_S(A, b + 2)
        DMA_S(A, 0)
        asm volatile("s_waitcnt vmcnt(8)" ::: "memory");  // B done
      } else {
        asm volatile("s_waitcnt vmcnt(0)" ::: "memory");  // B done (last)
      }
      __builtin_amdgcn_sched_barrier(0);
      CONSUME(B, 1)
    }
    if (b < nb) {  // odd batch count: final A still pending
      asm volatile("s_waitcnt vmcnt(0)" ::: "memory");
      __builtin_amdgcn_sched_barrier(0);
      CONSUME(A, 0)
    }
  }
  // tail (< 8 entries): plain loads, ascending, uniform k
  for (int i = nb * 8; i < len; ++i) {
    const int k = L16[i];
    const float4 w = *(const float4*)&WT[((size_t)k << 11) + n];
    if (k < KSPLIT) {
      lo0 += w.x; lo1 += w.y; lo2 += w.z; lo3 += w.w;
    } else {
      hi0 += w.x; hi1 += w.y; hi2 += w.z; hi3 += w.w;
    }
  }
#undef CONSUME
#undef ACC_SEL4
#undef ACC_HI4
#undef ACC_LO4
#undef DMA_S
#undef UNPACK_S

  *(float4*)&C[(size_t)tl * N_POST + n] =
      make_float4(lo0 + hi0, lo1 + hi1, lo2 + hi2, lo3 + hi3);  // rn(S1+S2)
}

// ---------------- Scan phase 1: checkpoint chain (32 waves) -----------------
// v9: full-tile prefetch (64 loads in flight). Chain ops identical to emit
// -> bitwise-equal v.
__global__ __launch_bounds__(64) void snn_scan_chk(const float* __restrict__ C,
                                                   float* __restrict__ vchk,
                                                   float* __restrict__ v_carry,
                                                   int ct, int first) {
  const int l = threadIdx.x;
  const int n = blockIdx.x * 64 + l;
  float v = 0.0f;
  if (!first) v = v_carry[n];
  const int ntiles = ct / 64;

  float cur[64], nxt[64];
#pragma unroll
  for (int j = 0; j < 64; ++j) cur[j] = C[(size_t)j * N_POST + n];

  for (int tile = 0; tile < ntiles; ++tile) {
    vchk[(size_t)tile * N_POST + n] = v;  // carry-in for this tile
    const int nb = (tile + 1) * 64;
    const bool hn = (tile + 1 < ntiles);
#pragma unroll
    for (int g = 0; g < 4; ++g) {
      if (hn) {
#pragma unroll
        for (int j = 0; j < 16; ++j)
          nxt[g * 16 + j] = C[(size_t)(nb + g * 16 + j) * N_POST + n];
      }
      // chain: 16 dependent LIF steps (DO NOT REORDER; identical to emit)
#pragma unroll
      for (int j = 0; j < 16; ++j) {
        const float c = cur[g * 16 + j];
        const float leak = opaque(v * 0.9f);  // rn(v*0.9f)
        v = leak + c;                         // rn(+c)
        const bool fired = (v >= 1.0f);
        v = fired ? 0.0f : v;
      }
    }
#pragma unroll
    for (int j = 0; j < 64; ++j) cur[j] = nxt[j];
  }
  v_carry[n] = v;
}

// ---------------- Scan phase 2: replay + emit (full chip) -------------------
// Block (n-group, tile): 1 wave, replays the 64-step chain from vchk with
// IDENTICAL ops/order (bitwise-equal s,v), stages in LDS [t][65], emits
// float4-wide on t. 2048 blocks -> full chip for the 64 MB of stores.
__global__ __launch_bounds__(64) void snn_scan_emit(const float* __restrict__ C,
                                                    const float* __restrict__ vchk,
                                                    float* __restrict__ spk,
                                                    float* __restrict__ vout,
                                                    int t0, int ct) {
  __shared__ float sb[64][65];
  __shared__ float vb[64][65];
  const int l = threadIdx.x;
  const int n0 = blockIdx.x * 64;
  const int tile = blockIdx.y;
  const int n = n0 + l;
  const int tb = tile * 64;

  float v = vchk[(size_t)tile * N_POST + n];

  float ccur[16], cnxt[16];
#pragma unroll
  for (int j = 0; j < 16; ++j) ccur[j] = C[(size_t)(tb + j) * N_POST + n];

#pragma unroll
  for (int g = 0; g < 4; ++g) {
    if (g < 3) {
#pragma unroll
      for (int j = 0; j < 16; ++j)
        cnxt[j] = C[(size_t)(tb + (g + 1) * 16 + j) * N_POST + n];
    }
    // chain: 16 dependent LIF steps (DO NOT REORDER; identical to chk)
#pragma unroll
    for (int j = 0; j < 16; ++j) {
      const float c = ccur[j];
      const float leak = opaque(v * 0.9f);  // rn(v*0.9f)
      v = leak + c;                         // rn(+c)
      const bool fired = (v >= 1.0f);
      sb[g * 16 + j][l] = fired ? 1.0f : 0.0f;
      v = fired ? 0.0f : v;
      vb[g * 16 + j][l] = v;
    }
#pragma unroll
    for (int j = 0; j < 16; ++j) ccur[j] = cnxt[j];
  }

  // flush: single wave => LDS program-order safe, no barrier needed.
  const int t4 = (l & 15) * 4;
  const int rq = l >> 4;
  const size_t gtb = (size_t)t0 + tb;
#pragma unroll
  for (int it = 0; it < 16; ++it) {
    const int r = it * 4 + rq;  // neuron row within group
    float4 so, vo;
    so.x = sb[t4 + 0][r]; so.y = sb[t4 + 1][r];
    so.z = sb[t4 + 2][r]; so.w = sb[t4 + 3][r];
    vo.x = vb[t4 + 0][r]; vo.y = vb[t4 + 1][r];
    vo.z = vb[t4 + 2][r]; vo.w = vb[t4 + 3][r];
    const size_t go = (size_t)(n0 + r) * SEQ_LEN + gtb + t4;
    *(float4*)&spk[go] = so;
    *(float4*)&vout[go] = vo;
  }
}

// ---------------- fused fallback (ws too small), same [512|512] chain -------
__global__ __launch_bounds__(256) void snn_fused_blis(const void* __restrict__ W,
                                                      const void* __restrict__ S,
                                                      float* __restrict__ spk,
                                                      float* __restrict__ vout) {
  __shared__ float As[16][68];
  __shared__ float Bs[16][68];
  __shared__ float Ct[64][65];
  __shared__ float vsh[64];
  __shared__ int flags_sh;
  const int tid = threadIdx.x;
  const int fl = sniff_flags(W, S, tid, &flags_sh);
  const bool w_bf = (fl & 1) != 0;
  const bool s_bf = (fl & 2) != 0;

  const int tx = tid & 15;
  const int ty = tid >> 4;
  const int m0 = blockIdx.x * 64;
  if (tid < 64) vsh[tid] = 0.0f;

  for (int t0 = 0; t0 < SEQ_LEN; t0 += 64) {
    float acc0[4][4] = {{0.f}};
    float acc1[4][4] = {{0.f}};
    int k0 = 0;
#define FUSED_SEGMENT(ACC, KEND)                                                 \
    for (; k0 < (KEND); k0 += 16) {                                              \
      {                                                                          \
        const int r = tid >> 4, c = tid & 15;                                    \
        _Pragma("unroll") for (int j = 0; j < 4; ++j)                            \
            As[c][r + 16 * j] =                                                  \
                load_dyn(W, (size_t)(m0 + r + 16 * j) * N_PRE + k0 + c, w_bf);   \
      }                                                                          \
      {                                                                          \
        const int r = tid >> 6, c = tid & 63;                                    \
        _Pragma("unroll") for (int j = 0; j < 4; ++j)                            \
            Bs[r + 4 * j][c] =                                                   \
                load_dyn(S, (size_t)(k0 + r + 4 * j) * SEQ_LEN + t0 + c, s_bf);  \
      }                                                                          \
      __syncthreads();                                                           \
      _Pragma("unroll") for (int k = 0; k < 16; ++k) {                           \
        _Pragma("unroll") for (int i = 0; i < 4; ++i)                            \
            _Pragma("unroll") for (int j = 0; j < 4; ++j)                        \
                ACC[i][j] += As[k][ty * 4 + i] * Bs[k][tx * 4 + j];              \
      }                                                                          \
      __syncthreads();                                                           \
    }

    FUSED_SEGMENT(acc0, KSPLIT)
    FUSED_SEGMENT(acc1, N_PRE)
#undef FUSED_SEGMENT

#pragma unroll
    for (int i = 0; i < 4; ++i)
#pragma unroll
      for (int j = 0; j < 4; ++j) Ct[ty * 4 + i][tx * 4 + j] = acc0[i][j] + acc1[i][j];
    __syncthreads();
    if (tid < 64) {
      float v = vsh[tid];
#pragma unroll
      for (int k = 0; k < 64; ++k) {
        const float leak = opaque(v * 0.9f);
        v = leak + Ct[tid][k];
        const bool fired = (v >= 1.0f);
        const size_t g = (size_t)(m0 + tid) * SEQ_LEN + t0 + k;
        spk[g] = fired ? 1.0f : 0.0f;
        v = fired ? 0.0f : v;
        vout[g] = v;
      }
      vsh[tid] = v;
    }
    __syncthreads();
  }
}

extern "C" void kernel_launch(void* const* d_in, const int* in_sizes, int n_in,
                              void* d_out, int out_size, void* d_ws, size_t ws_size,
                              hipStream_t stream) {
  const void* stim = d_in[0];
  const void* weights = d_in[1];
  if (n_in >= 2 && in_sizes[0] == N_POST * N_PRE && in_sizes[1] == N_PRE * SEQ_LEN) {
    weights = d_in[0];
    stim = d_in[1];
  }

  float* spk = (float*)d_out;                    // output 0: spikes [N_POST, SEQ_LEN]
  float* vout = spk + (size_t)N_POST * SEQ_LEN;  // output 1: v      [N_POST, SEQ_LEN]

  // ---- workspace carve ----
  char* p = (char*)d_ws;
  float* WT = (float*)p;                 p += (size_t)N_PRE * N_POST * 4;      // 8 MB
  unsigned char* MT = (unsigned char*)p; p += (size_t)(SEQ_LEN / 8) * N_PRE;   // 512 KB
  unsigned short* lists = (unsigned short*)p; p += (size_t)SEQ_LEN * N_PRE * 2;// 8 MB
  int* lens = (int*)p;                   p += (size_t)SEQ_LEN * 4;             // 16 KB
  float* v_carry = (float*)p;            p += (size_t)N_POST * 4;              // 8 KB
  float* vchk = (float*)p;               p += (size_t)(SEQ_LEN / 64) * N_POST * 4;  // 512 KB
  float* C = (float*)p;
  const size_t used = (size_t)(p - (char*)d_ws);
  const size_t remain = (ws_size > used) ? (ws_size - used) : 0;

  int chunkT = (int)((remain / ((size_t)N_POST * sizeof(float))) / 64 * 64);
  if (chunkT > SEQ_LEN) chunkT = SEQ_LEN;
  if (chunkT >= 64) {  // round to power of two so chunkT divides SEQ_LEN
    int pw = 64;
    while (pw * 2 <= chunkT && pw < SEQ_LEN) pw *= 2;
    chunkT = pw;
  }

  if (chunkT >= 64) {
    snn_wt_build<<<dim3(N_PRE / 64, N_POST / 64), dim3(256), 0, stream>>>(weights, stim, WT);
    snn_mask_build<<<dim3(SEQ_LEN / 8), dim3(64), 0, stream>>>(weights, stim, MT);
    snn_list_build<<<dim3(SEQ_LEN), dim3(64), 0, stream>>>(MT, lists, lens);
    for (int t0 = 0; t0 < SEQ_LEN; t0 += chunkT) {
      const int ct = (SEQ_LEN - t0 < chunkT) ? (SEQ_LEN - t0) : chunkT;  // mult of 64
      snn_gemm_sp<<<dim3(ct * 8), dim3(64), 0, stream>>>(WT, lists, lens, C, t0, ct);
      snn_scan_chk<<<dim3(N_POST / 64), dim3(64), 0, stream>>>(C, vchk, v_carry,
                                                               ct, t0 == 0);
      snn_scan_emit<<<dim3(N_POST / 64, ct / 64), dim3(64), 0, stream>>>(C, vchk, spk,
                                                                         vout, t0, ct);
    }
  } else {
    snn_fused_blis<<<dim3(N_POST / 64), dim3(256), 0, stream>>>(weights, stim, spk, vout);
  }
}

// Round 17
// 363.165 us; speedup vs baseline: 1.0159x; 1.0159x over previous
//
#include <hip/hip_runtime.h>

#define N_PRE 1024
#define N_POST 2048
#define SEQ_LEN 4096

// Reference-verified numerics (R11 PASS): per C element two fp32 segment
// chains k in [0,512) and [512,1024), ascending, single accumulator each,
// combined rn(S1+S2). stim in {0,1} -> products exact -> FMA == mul+add.
// Scan: v = rn(rn(v*0.9f) + c), fire >= 1.0f, reset 0. DO NOT REORDER.
//
// Sparse (v6, PASS absmax 0.015625): skipping adds of exact +/-0.0 is
// BIT-IDENTICAL (acc starts +0.0; RN never yields -0.0 from a sum).
//
// v11/v13/v14 (123-148us) proved the per-(t,spike) gather formulation is at
// its per-CU ceiling (~22 B/cyc/CU TA path; occupancy/MLP/DMA all null).
// v15: LDS-paneled GEMM. 32-k WT panels double-buffered in LDS (DMA-staged),
// consumed by 64 t's per block via per-t 32-bit spike masks (MT2). Global
// WT traffic 3.34GB -> ~0.5GB; consume moves to the LDS pipe (~65us floor).
// Panels ascend, mask bits ascend, panel 0-15 = lo (k<512), 16-31 = hi ->
// same per-segment ascending add order -> bit-identical.
#define KSPLIT 512
#define TB 64   // t's per block
#define PK 32   // k-rows per panel

__device__ __forceinline__ float opaque(float x) {
  asm volatile("" : "+v"(x));
  return x;
}

__device__ __forceinline__ float load_dyn(const void* p, size_t idx, bool isbf) {
  if (isbf) {
    const unsigned short b = ((const unsigned short*)p)[idx];
    return __uint_as_float(((unsigned int)b) << 16);
  }
  return ((const float*)p)[idx];
}

// Input-dtype sniff (established: weights fp32, stim bf16; kept for safety).
__device__ __forceinline__ int sniff_flags(const void* W, const void* S, int tid,
                                           int* flags_sh) {
  if (tid < 64) {
    const unsigned short* uw = (const unsigned short*)W;
    const float f = fabsf(__uint_as_float(((unsigned int)uw[tid * 2]) << 16));
    const bool big = !(f < 64.f);
    const unsigned long long wb = __ballot(big);
    const unsigned short* us = (const unsigned short*)S;
    int hit = 0;
    for (int j = 0; j < 64; ++j) hit |= (us[tid * 128 + 2 * j] == 0x3F80u) ? 1 : 0;
    const unsigned long long sb = __ballot(hit != 0);
    if (tid == 0) *flags_sh = ((wb == 0ull) ? 1 : 0) | ((sb != 0ull) ? 2 : 0);
  }
  __syncthreads();
  return *flags_sh;
}

// ---------------- WT build: W[n][k] -> WT[k][n] (fp32), LDS transpose -------
__global__ __launch_bounds__(256) void snn_wt_build(const void* __restrict__ W,
                                                    const void* __restrict__ S,
                                                    float* __restrict__ WT) {
  __shared__ float tile[64][65];
  __shared__ int flags_sh;
  const int tid = threadIdx.x;
  const int fl = sniff_flags(W, S, tid, &flags_sh);
  const bool w_bf = (fl & 1) != 0;
  const int k0 = blockIdx.x * 64;
  const int nn0 = blockIdx.y * 64;
  {
    const int r = tid >> 2;
    const int cq = tid & 3;
    if (!w_bf) {
      const float* Wf = (const float*)W;
#pragma unroll
      for (int p = 0; p < 4; ++p) {
        const int c = cq * 16 + p * 4;
        const float4 va = *(const float4*)&Wf[(size_t)(nn0 + r) * N_PRE + k0 + c];
        tile[c + 0][r] = va.x; tile[c + 1][r] = va.y;
        tile[c + 2][r] = va.z; tile[c + 3][r] = va.w;
      }
    } else {
#pragma unroll
      for (int p = 0; p < 4; ++p)
#pragma unroll
        for (int j = 0; j < 4; ++j) {
          const int c = cq * 16 + p * 4 + j;
          tile[c][r] = load_dyn(W, (size_t)(nn0 + r) * N_PRE + k0 + c, true);
        }
    }
  }
  __syncthreads();
  {
    const int kr = tid >> 2;
    const int nq = tid & 3;
#pragma unroll
    for (int p = 0; p < 4; ++p) {
      const int c = nq * 16 + p * 4;
      float4 o;
      o.x = tile[kr][c + 0]; o.y = tile[kr][c + 1];
      o.z = tile[kr][c + 2]; o.w = tile[kr][c + 3];
      *(float4*)&WT[(size_t)(k0 + kr) * N_POST + nn0 + c] = o;
    }
  }
}

// ---------------- mask build: stim -> MT[t/8][k] bitmask bytes --------------
__global__ __launch_bounds__(64) void snn_mask_build(const void* __restrict__ W,
                                                     const void* __restrict__ S,
                                                     unsigned char* __restrict__ MT) {
  __shared__ int flags_sh;
  const int tid = threadIdx.x;
  const int fl = sniff_flags(W, S, tid, &flags_sh);
  const bool s_bf = (fl & 2) != 0;
  const int tb = blockIdx.x;  // t-byte index: t = tb*8 + bit
  unsigned wrd[4] = {0u, 0u, 0u, 0u};
#pragma unroll
  for (int kk = 0; kk < 16; ++kk) {
    const int k = tid * 16 + kk;
    unsigned byte = 0;
    if (s_bf) {
      const unsigned short* Sb = (const unsigned short*)S;
      const uint4 u = *(const uint4*)&Sb[(size_t)k * SEQ_LEN + tb * 8];
      byte |= (((u.x & 0x7FFFu) != 0u) ? 1u : 0u) << 0;
      byte |= (((u.x & 0x7FFF0000u) != 0u) ? 1u : 0u) << 1;
      byte |= (((u.y & 0x7FFFu) != 0u) ? 1u : 0u) << 2;
      byte |= (((u.y & 0x7FFF0000u) != 0u) ? 1u : 0u) << 3;
      byte |= (((u.z & 0x7FFFu) != 0u) ? 1u : 0u) << 4;
      byte |= (((u.z & 0x7FFF0000u) != 0u) ? 1u : 0u) << 5;
      byte |= (((u.w & 0x7FFFu) != 0u) ? 1u : 0u) << 6;
      byte |= (((u.w & 0x7FFF0000u) != 0u) ? 1u : 0u) << 7;
    } else {
      const float* Sf = (const float*)S;
      const size_t base = (size_t)k * SEQ_LEN + tb * 8;
      const float4 f0 = *(const float4*)&Sf[base];
      const float4 f1 = *(const float4*)&Sf[base + 4];
      byte |= ((f0.x != 0.0f) ? 1u : 0u) << 0;
      byte |= ((f0.y != 0.0f) ? 1u : 0u) << 1;
      byte |= ((f0.z != 0.0f) ? 1u : 0u) << 2;
      byte |= ((f0.w != 0.0f) ? 1u : 0u) << 3;
      byte |= ((f1.x != 0.0f) ? 1u : 0u) << 4;
      byte |= ((f1.y != 0.0f) ? 1u : 0u) << 5;
      byte |= ((f1.z != 0.0f) ? 1u : 0u) << 6;
      byte |= ((f1.w != 0.0f) ? 1u : 0u) << 7;
    }
    wrd[kk >> 2] |= byte << ((kk & 3) * 8);
  }
  *(uint4*)&MT[(size_t)tb * N_PRE + tid * 16] =
      make_uint4(wrd[0], wrd[1], wrd[2], wrd[3]);
}

// ---------------- mask2 build: MT -> MT2[t][w] u32 (bit j = k=32w+j) --------
__global__ __launch_bounds__(64) void snn_mask2_build(const unsigned char* __restrict__ MT,
                                                      unsigned* __restrict__ MT2) {
  const int t = blockIdx.x;
  const int w = threadIdx.x;  // 0..63, active < 32
  if (w < 32) {
    const unsigned char* row = MT + (size_t)(t >> 3) * N_PRE + w * 32;
    const int bt = t & 7;
    unsigned m = 0;
#pragma unroll
    for (int j = 0; j < 32; ++j) m |= (unsigned)((row[j] >> bt) & 1) << j;
    MT2[(size_t)t * 32 + w] = m;
  }
}

// ---------------- paneled sparse GEMM: C[t][n] = sum_k spike WT[k][n] -------
// Block = 256 thr (4 waves) x (64-t block, 256-n slice); slice = bid&7 (XCD
// pinning, v11-verified). 32-k WT panels double-buffered in LDS via
// global_load_lds DMA; per-t spike masks staged in LDS. Inner loop has no
// global deps: while(m){b=ffs;ds_read panel[b];add}. Wave-uniform masks ->
// no divergence. Panels+bits ascend; p<16 = lo, p>=16 = hi; rn(lo+hi).
__global__ __launch_bounds__(256, 2) void snn_gemm_panel(const float* __restrict__ WT,
                                                         const unsigned* __restrict__ MT2,
                                                         float* __restrict__ C,
                                                         int t0, int ct) {
  __shared__ float panel[2][PK][256];  // 2 x 32 KB
  __shared__ unsigned msh[TB * 32];    // 8 KB mask cache
  const int slice = (int)blockIdx.x & 7;
  const int tq = (int)blockIdx.x >> 3;
  const int tid = (int)threadIdx.x;
  const int wid = tid >> 6;
  const int lane = tid & 63;
  const int tbl = tq * TB;         // chunk-local t base
  const int tbg = t0 + tbl;        // global t base
  const int ncol = slice * 256 + lane * 4;

  // stage this block's masks (TB*32 u32, contiguous in MT2)
  {
    const unsigned* src = &MT2[(size_t)tbg * 32];
    for (int i = tid; i < TB * 32; i += 256) msh[i] = src[i];
  }

#define STAGE(P, BUF)                                                          \
  {                                                                            \
    const int kb = (P) * PK + wid * 8;                                         \
    _Pragma("unroll") for (int r = 0; r < 8; ++r) {                            \
      __builtin_amdgcn_global_load_lds(                                        \
          &WT[((size_t)(kb + r) << 11) + ncol], &panel[BUF][wid * 8 + r][lane * 4], \
          16, 0, 0);                                                           \
    }                                                                          \
  }

  float lo[16][4], ac[16][4];
#pragma unroll
  for (int j = 0; j < 16; ++j) {
    lo[j][0] = lo[j][1] = lo[j][2] = lo[j][3] = 0.f;
    ac[j][0] = ac[j][1] = ac[j][2] = ac[j][3] = 0.f;
  }

  STAGE(0, 0)
  asm volatile("s_waitcnt vmcnt(0)" ::: "memory");
  __syncthreads();  // panel 0 + masks visible to all waves

  for (int p = 0; p < 32; ++p) {
    const int buf = p & 1;
    if (p + 1 < 32) STAGE(p + 1, buf ^ 1)
    // consume panel p for this wave's 16 t's (mask wave-uniform -> no div)
#pragma unroll
    for (int j = 0; j < 16; ++j) {
      unsigned m = msh[(wid * 16 + j) * 32 + p];
      while (m) {
        const int b = __ffs(m) - 1;  // ascending bit = ascending k
        m &= m - 1;
        const float4 w4 = *(const float4*)&panel[buf][b][lane * 4];
        ac[j][0] += w4.x; ac[j][1] += w4.y; ac[j][2] += w4.z; ac[j][3] += w4.w;
      }
    }
    if (p == 15) {  // end of lo segment (k<512): save and reset
#pragma unroll
      for (int j = 0; j < 16; ++j) {
        lo[j][0] = ac[j][0]; lo[j][1] = ac[j][1];
        lo[j][2] = ac[j][2]; lo[j][3] = ac[j][3];
        ac[j][0] = ac[j][1] = ac[j][2] = ac[j][3] = 0.f;
      }
    }
    asm volatile("s_waitcnt vmcnt(0)" ::: "memory");  // next panel landed
    __syncthreads();                                  // all waves done with buf
  }
#undef STAGE

#pragma unroll
  for (int j = 0; j < 16; ++j) {
    float* dst = &C[(size_t)(tbl + wid * 16 + j) * N_POST + ncol];
    *(float4*)dst = make_float4(lo[j][0] + ac[j][0], lo[j][1] + ac[j][1],
                                lo[j][2] + ac[j][2], lo[j][3] + ac[j][3]);
  }
}

// ---------------- Scan phase 1: checkpoint chain (32 waves) -----------------
// v9: full-tile prefetch (64 loads in flight). Chain ops identical to emit
// -> bitwise-equal v.
__global__ __launch_bounds__(64) void snn_scan_chk(const float* __restrict__ C,
                                                   float* __restrict__ vchk,
                                                   float* __restrict__ v_carry,
                                                   int ct, int first) {
  const int l = threadIdx.x;
  const int n = blockIdx.x * 64 + l;
  float v = 0.0f;
  if (!first) v = v_carry[n];
  const int ntiles = ct / 64;

  float cur[64], nxt[64];
#pragma unroll
  for (int j = 0; j < 64; ++j) cur[j] = C[(size_t)j * N_POST + n];

  for (int tile = 0; tile < ntiles; ++tile) {
    vchk[(size_t)tile * N_POST + n] = v;  // carry-in for this tile
    const int nb = (tile + 1) * 64;
    const bool hn = (tile + 1 < ntiles);
#pragma unroll
    for (int g = 0; g < 4; ++g) {
      if (hn) {
#pragma unroll
        for (int j = 0; j < 16; ++j)
          nxt[g * 16 + j] = C[(size_t)(nb + g * 16 + j) * N_POST + n];
      }
      // chain: 16 dependent LIF steps (DO NOT REORDER; identical to emit)
#pragma unroll
      for (int j = 0; j < 16; ++j) {
        const float c = cur[g * 16 + j];
        const float leak = opaque(v * 0.9f);  // rn(v*0.9f)
        v = leak + c;                         // rn(+c)
        const bool fired = (v >= 1.0f);
        v = fired ? 0.0f : v;
      }
    }
#pragma unroll
    for (int j = 0; j < 64; ++j) cur[j] = nxt[j];
  }
  v_carry[n] = v;
}

// ---------------- Scan phase 2: replay + emit (full chip) -------------------
// Block (n-group, tile): 1 wave, replays the 64-step chain from vchk with
// IDENTICAL ops/order (bitwise-equal s,v), stages in LDS [t][65], emits
// float4-wide on t. 2048 blocks -> full chip for the 64 MB of stores.
__global__ __launch_bounds__(64) void snn_scan_emit(const float* __restrict__ C,
                                                    const float* __restrict__ vchk,
                                                    float* __restrict__ spk,
                                                    float* __restrict__ vout,
                                                    int t0, int ct) {
  __shared__ float sb[64][65];
  __shared__ float vb[64][65];
  const int l = threadIdx.x;
  const int n0 = blockIdx.x * 64;
  const int tile = blockIdx.y;
  const int n = n0 + l;
  const int tb = tile * 64;

  float v = vchk[(size_t)tile * N_POST + n];

  float ccur[16], cnxt[16];
#pragma unroll
  for (int j = 0; j < 16; ++j) ccur[j] = C[(size_t)(tb + j) * N_POST + n];

#pragma unroll
  for (int g = 0; g < 4; ++g) {
    if (g < 3) {
#pragma unroll
      for (int j = 0; j < 16; ++j)
        cnxt[j] = C[(size_t)(tb + (g + 1) * 16 + j) * N_POST + n];
    }
    // chain: 16 dependent LIF steps (DO NOT REORDER; identical to chk)
#pragma unroll
    for (int j = 0; j < 16; ++j) {
      const float c = ccur[j];
      const float leak = opaque(v * 0.9f);  // rn(v*0.9f)
      v = leak + c;                         // rn(+c)
      const bool fired = (v >= 1.0f);
      sb[g * 16 + j][l] = fired ? 1.0f : 0.0f;
      v = fired ? 0.0f : v;
      vb[g * 16 + j][l] = v;
    }
#pragma unroll
    for (int j = 0; j < 16; ++j) ccur[j] = cnxt[j];
  }

  // flush: single wave => LDS program-order safe, no barrier needed.
  const int t4 = (l & 15) * 4;
  const int rq = l >> 4;
  const size_t gtb = (size_t)t0 + tb;
#pragma unroll
  for (int it = 0; it < 16; ++it) {
    const int r = it * 4 + rq;  // neuron row within group
    float4 so, vo;
    so.x = sb[t4 + 0][r]; so.y = sb[t4 + 1][r];
    so.z = sb[t4 + 2][r]; so.w = sb[t4 + 3][r];
    vo.x = vb[t4 + 0][r]; vo.y = vb[t4 + 1][r];
    vo.z = vb[t4 + 2][r]; vo.w = vb[t4 + 3][r];
    const size_t go = (size_t)(n0 + r) * SEQ_LEN + gtb + t4;
    *(float4*)&spk[go] = so;
    *(float4*)&vout[go] = vo;
  }
}

// ---------------- fused fallback (ws too small), same [512|512] chain -------
__global__ __launch_bounds__(256) void snn_fused_blis(const void* __restrict__ W,
                                                      const void* __restrict__ S,
                                                      float* __restrict__ spk,
                                                      float* __restrict__ vout) {
  __shared__ float As[16][68];
  __shared__ float Bs[16][68];
  __shared__ float Ct[64][65];
  __shared__ float vsh[64];
  __shared__ int flags_sh;
  const int tid = threadIdx.x;
  const int fl = sniff_flags(W, S, tid, &flags_sh);
  const bool w_bf = (fl & 1) != 0;
  const bool s_bf = (fl & 2) != 0;

  const int tx = tid & 15;
  const int ty = tid >> 4;
  const int m0 = blockIdx.x * 64;
  if (tid < 64) vsh[tid] = 0.0f;

  for (int t0 = 0; t0 < SEQ_LEN; t0 += 64) {
    float acc0[4][4] = {{0.f}};
    float acc1[4][4] = {{0.f}};
    int k0 = 0;
#define FUSED_SEGMENT(ACC, KEND)                                                 \
    for (; k0 < (KEND); k0 += 16) {                                              \
      {                                                                          \
        const int r = tid >> 4, c = tid & 15;                                    \
        _Pragma("unroll") for (int j = 0; j < 4; ++j)                            \
            As[c][r + 16 * j] =                                                  \
                load_dyn(W, (size_t)(m0 + r + 16 * j) * N_PRE + k0 + c, w_bf);   \
      }                                                                          \
      {                                                                          \
        const int r = tid >> 6, c = tid & 63;                                    \
        _Pragma("unroll") for (int j = 0; j < 4; ++j)                            \
            Bs[r + 4 * j][c] =                                                   \
                load_dyn(S, (size_t)(k0 + r + 4 * j) * SEQ_LEN + t0 + c, s_bf);  \
      }                                                                          \
      __syncthreads();                                                           \
      _Pragma("unroll") for (int k = 0; k < 16; ++k) {                           \
        _Pragma("unroll") for (int i = 0; i < 4; ++i)                            \
            _Pragma("unroll") for (int j = 0; j < 4; ++j)                        \
                ACC[i][j] += As[k][ty * 4 + i] * Bs[k][tx * 4 + j];              \
      }                                                                          \
      __syncthreads();                                                           \
    }

    FUSED_SEGMENT(acc0, KSPLIT)
    FUSED_SEGMENT(acc1, N_PRE)
#undef FUSED_SEGMENT

#pragma unroll
    for (int i = 0; i < 4; ++i)
#pragma unroll
      for (int j = 0; j < 4; ++j) Ct[ty * 4 + i][tx * 4 + j] = acc0[i][j] + acc1[i][j];
    __syncthreads();
    if (tid < 64) {
      float v = vsh[tid];
#pragma unroll
      for (int k = 0; k < 64; ++k) {
        const float leak = opaque(v * 0.9f);
        v = leak + Ct[tid][k];
        const bool fired = (v >= 1.0f);
        const size_t g = (size_t)(m0 + tid) * SEQ_LEN + t0 + k;
        spk[g] = fired ? 1.0f : 0.0f;
        v = fired ? 0.0f : v;
        vout[g] = v;
      }
      vsh[tid] = v;
    }
    __syncthreads();
  }
}

extern "C" void kernel_launch(void* const* d_in, const int* in_sizes, int n_in,
                              void* d_out, int out_size, void* d_ws, size_t ws_size,
                              hipStream_t stream) {
  const void* stim = d_in[0];
  const void* weights = d_in[1];
  if (n_in >= 2 && in_sizes[0] == N_POST * N_PRE && in_sizes[1] == N_PRE * SEQ_LEN) {
    weights = d_in[0];
    stim = d_in[1];
  }

  float* spk = (float*)d_out;                    // output 0: spikes [N_POST, SEQ_LEN]
  float* vout = spk + (size_t)N_POST * SEQ_LEN;  // output 1: v      [N_POST, SEQ_LEN]

  // ---- workspace carve ----
  char* p = (char*)d_ws;
  float* WT = (float*)p;                 p += (size_t)N_PRE * N_POST * 4;      // 8 MB
  unsigned char* MT = (unsigned char*)p; p += (size_t)(SEQ_LEN / 8) * N_PRE;   // 512 KB
  unsigned* MT2 = (unsigned*)p;          p += (size_t)SEQ_LEN * 32 * 4;        // 512 KB
  float* v_carry = (float*)p;            p += (size_t)N_POST * 4;              // 8 KB
  float* vchk = (float*)p;               p += (size_t)(SEQ_LEN / 64) * N_POST * 4;  // 512 KB
  float* C = (float*)p;
  const size_t used = (size_t)(p - (char*)d_ws);
  const size_t remain = (ws_size > used) ? (ws_size - used) : 0;

  int chunkT = (int)((remain / ((size_t)N_POST * sizeof(float))) / 64 * 64);
  if (chunkT > SEQ_LEN) chunkT = SEQ_LEN;
  if (chunkT >= 64) {  // round to power of two so chunkT divides SEQ_LEN
    int pw = 64;
    while (pw * 2 <= chunkT && pw < SEQ_LEN) pw *= 2;
    chunkT = pw;
  }

  if (chunkT >= 64) {
    snn_wt_build<<<dim3(N_PRE / 64, N_POST / 64), dim3(256), 0, stream>>>(weights, stim, WT);
    snn_mask_build<<<dim3(SEQ_LEN / 8), dim3(64), 0, stream>>>(weights, stim, MT);
    snn_mask2_build<<<dim3(SEQ_LEN), dim3(64), 0, stream>>>(MT, MT2);
    for (int t0 = 0; t0 < SEQ_LEN; t0 += chunkT) {
      const int ct = (SEQ_LEN - t0 < chunkT) ? (SEQ_LEN - t0) : chunkT;  // mult of 64
      snn_gemm_panel<<<dim3((ct / TB) * 8), dim3(256), 0, stream>>>(WT, MT2, C, t0, ct);
      snn_scan_chk<<<dim3(N_POST / 64), dim3(64), 0, stream>>>(C, vchk, v_carry,
                                                               ct, t0 == 0);
      snn_scan_emit<<<dim3(N_POST / 64, ct / 64), dim3(64), 0, stream>>>(C, vchk, spk,
                                                                         vout, t0, ct);
    }
  } else {
    snn_fused_blis<<<dim3(N_POST / 64), dim3(256), 0, stream>>>(weights, stim, spk, vout);
  }
}